// Round 1
// baseline (497.875 us; speedup 1.0000x reference)
//
#include <hip/hip_runtime.h>
#include <cstdint>
#include <cstddef>

// Paged GQA flash-decode attention, fp32, split-KV two-pass.
// B=16 H=32 D=128 T=4096 KVH=8 G=4.  Memory-bound: ~268MB KV traffic -> ~45us floor.

#define NB 16
#define NH 32
#define HD 128
#define NT 4096
#define NKVH 8
#define NG 4
#define NSPLIT 16
#define CHUNK (NT / NSPLIT)      // 256 tokens per block
#define TILE_T 16                // tokens per wave-tile
#define NWAVE 4
#define ROW 132                  // padded LDS row stride (floats); 132*4=528B, 16B-aligned
#define PART_STRIDE 520          // per-(b,kvh,split): o[4][128] + m[4] + l[4]
#define SCALE_F 0.08838834764831845f

// Compile-time ordering fence for wave-synchronous LDS use (HW LDS is in-order per wave).
__device__ __forceinline__ void wave_sync() {
    __builtin_amdgcn_wave_barrier();
    __asm__ volatile("" ::: "memory");
}

__global__ __launch_bounds__(256) void attn_partial_kernel(
    const float* __restrict__ q,
    const float* __restrict__ kc,
    const float* __restrict__ vc,
    const int*   __restrict__ kv_lens,
    const int*   __restrict__ btab,
    float*       __restrict__ part)
{
    __shared__ float q_lds[NG][ROW];                    // 2112 B
    __shared__ float kv_lds[NWAVE][TILE_T][ROW];        // 33792 B (K, then reused for V)
    __shared__ float p_lds[NWAVE][TILE_T][NG];          // 1024 B
    __shared__ float a_lds[NWAVE][NG];                  // 64 B
    __shared__ float ml_lds[NWAVE][NG][2];              // 128 B
    // total ~37.1 KB -> 4 blocks/CU -> 16 waves/CU

    const int bid = blockIdx.x;                 // = (b*NKVH + kvh)*NSPLIT + c
    const int c   = bid % NSPLIT;
    const int kvh = (bid / NSPLIT) % NKVH;
    const int b   = bid / (NSPLIT * NKVH);
    const int tid  = threadIdx.x;
    const int w    = tid >> 6;
    const int lane = tid & 63;

    const int kv_len = kv_lens[b];              // global_kv_lens shape (1,B)
    const int t0c = c * CHUNK;
    const int t1c = min(t0c + CHUNK, kv_len);

    float* pb = part + (size_t)bid * PART_STRIDE;

    if (t0c >= kv_len) {
        // empty chunk: m=-1e30, l=0, o=0 (combine kernel zeroes its contribution)
        for (int i = tid; i < PART_STRIDE; i += 256)
            pb[i] = (i >= 512 && i < 516) ? -1e30f : 0.0f;
        return;
    }

    // stage q[b, kvh*G+g, :] for g=0..3 into LDS (padded rows -> conflict-free bcast reads)
    {
        int g  = tid >> 6;
        int dd = (tid & 63) * 2;
        const float* qp = q + ((size_t)(b * NH + kvh * NG + g)) * HD + dd;
        q_lds[g][dd]     = qp[0];
        q_lds[g][dd + 1] = qp[1];
    }
    __syncthreads();   // only block-wide barrier before the K-loop

    float m_g = -1e30f;       // per-lane, consistent across same-g lanes
    float l_g = 0.0f;
    float o00=0,o01=0,o10=0,o11=0,o20=0,o21=0,o30=0,o31=0;  // o[g][2] in PV layout

    const int half = lane >> 5;       // staging: which of 2 rows this half-wave loads
    const int d4   = lane & 31;       // staging: float4 index within row
    const int tt_s = lane >> 2;       // score layout: token within tile
    const int g_s  = lane & 3;        // score layout: query-group head
    const int dp   = lane * 2;        // PV layout: d-pair owned by lane

    for (int t0 = t0c + w * TILE_T; t0 < t1c; t0 += NWAVE * TILE_T) {
        // page ids for this tile (clamped for tail lanes; masked later)
        int pg = 0;
        if (lane < TILE_T) {
            int t = t0 + lane;
            pg = btab[b * NT + ((t < t1c) ? t : t0)];
        }

        // stage K tile -> LDS; issue V loads into registers early (latency overlap)
        float4 vreg[8];
        #pragma unroll
        for (int r = 0; r < 8; ++r) {
            int tt = r * 2 + half;
            int page = __shfl(pg, tt);
            const float4 kk = *((const float4*)(kc + (size_t)page * (NKVH * HD) + kvh * HD) + d4);
            *(float4*)&kv_lds[w][tt][d4 * 4] = kk;
        }
        #pragma unroll
        for (int r = 0; r < 8; ++r) {
            int tt = r * 2 + half;
            int page = __shfl(pg, tt);
            vreg[r] = *((const float4*)(vc + (size_t)page * (NKVH * HD) + kvh * HD) + d4);
        }
        wave_sync();

        // scores: lane (tt_s, g_s) computes full 128-d dot from LDS (q row broadcast)
        float s = 0.0f;
        #pragma unroll
        for (int i = 0; i < 32; ++i) {
            float4 kk = *(const float4*)&kv_lds[w][tt_s][i * 4];
            float4 qq = *(const float4*)&q_lds[g_s][i * 4];
            s = fmaf(kk.x, qq.x, s);
            s = fmaf(kk.y, qq.y, s);
            s = fmaf(kk.z, qq.z, s);
            s = fmaf(kk.w, qq.w, s);
        }
        s *= SCALE_F;
        if (t0 + tt_s >= t1c) s = -1e30f;      // tail mask

        // online softmax over this tile, per g (16 same-g lanes: xor 4,8,16,32)
        float tmax = s;
        #pragma unroll
        for (int off = 4; off < 64; off <<= 1)
            tmax = fmaxf(tmax, __shfl_xor(tmax, off));
        float m_new = fmaxf(m_g, tmax);
        float alpha = __expf(m_g - m_new);     // exp(-1e30 - finite) = 0, no NaN
        float p     = __expf(s - m_new);       // masked lanes -> 0
        float tsum = p;
        #pragma unroll
        for (int off = 4; off < 64; off <<= 1)
            tsum += __shfl_xor(tsum, off);
        l_g = l_g * alpha + tsum;
        m_g = m_new;

        p_lds[w][tt_s][g_s] = p;
        if (tt_s == 0) a_lds[w][g_s] = alpha;
        wave_sync();   // also fences: score reads done before V overwrites the buffer

        // store V tile over the K tile (WAR safe: LDS in-order per wave)
        #pragma unroll
        for (int r = 0; r < 8; ++r) {
            int tt = r * 2 + half;
            *(float4*)&kv_lds[w][tt][d4 * 4] = vreg[r];
        }
        wave_sync();

        // PV: lane owns d-pair dp; p broadcast per token
        float a0 = a_lds[w][0], a1 = a_lds[w][1], a2 = a_lds[w][2], a3 = a_lds[w][3];
        o00 *= a0; o01 *= a0; o10 *= a1; o11 *= a1;
        o20 *= a2; o21 *= a2; o30 *= a3; o31 *= a3;
        #pragma unroll
        for (int t = 0; t < TILE_T; ++t) {
            float2 vv = *(const float2*)&kv_lds[w][t][dp];
            float4 pp = *(const float4*)&p_lds[w][t][0];   // broadcast
            o00 = fmaf(pp.x, vv.x, o00); o01 = fmaf(pp.x, vv.y, o01);
            o10 = fmaf(pp.y, vv.x, o10); o11 = fmaf(pp.y, vv.y, o11);
            o20 = fmaf(pp.z, vv.x, o20); o21 = fmaf(pp.z, vv.y, o21);
            o30 = fmaf(pp.w, vv.x, o30); o31 = fmaf(pp.w, vv.y, o31);
        }
        wave_sync();   // PV reads done before next iter's K staging overwrites
    }

    // cross-wave combine within block: each wave dumps state into ITS OWN kv_lds region
    {
        float* ow = &kv_lds[w][0][0];          // 2048 floats needed, 2112 available
        ow[0 * HD + dp] = o00; ow[0 * HD + dp + 1] = o01;
        ow[1 * HD + dp] = o10; ow[1 * HD + dp + 1] = o11;
        ow[2 * HD + dp] = o20; ow[2 * HD + dp + 1] = o21;
        ow[3 * HD + dp] = o30; ow[3 * HD + dp + 1] = o31;
        if (tt_s == 0) { ml_lds[w][g_s][0] = m_g; ml_lds[w][g_s][1] = l_g; }
    }
    __syncthreads();

    {
        int g  = tid >> 6;
        int d2 = (tid & 63) * 2;
        float M = fmaxf(fmaxf(ml_lds[0][g][0], ml_lds[1][g][0]),
                        fmaxf(ml_lds[2][g][0], ml_lds[3][g][0]));
        float L = 0.0f, O0 = 0.0f, O1 = 0.0f;
        #pragma unroll
        for (int wv = 0; wv < NWAVE; ++wv) {
            float sc = __expf(ml_lds[wv][g][0] - M);   // empty wave: exp(-1e30-M)=0
            L  += ml_lds[wv][g][1] * sc;
            const float* owv = &kv_lds[wv][0][0];
            O0 += owv[g * HD + d2]     * sc;
            O1 += owv[g * HD + d2 + 1] * sc;
        }
        pb[g * HD + d2]     = O0;      // unnormalized partial
        pb[g * HD + d2 + 1] = O1;
        if ((tid & 63) == 0) { pb[512 + g] = M; pb[516 + g] = L; }
    }
}

__global__ __launch_bounds__(256) void attn_combine_kernel(
    const float* __restrict__ part, float* __restrict__ out)
{
    const int bid = blockIdx.x;        // b*NKVH + kvh
    const int tid = threadIdx.x;
    const int g  = tid >> 6;
    const int d2 = (tid & 63) * 2;
    const int b   = bid / NKVH;
    const int kvh = bid % NKVH;
    const float* pb = part + (size_t)bid * NSPLIT * PART_STRIDE;

    float M = -1e30f;
    #pragma unroll
    for (int cc = 0; cc < NSPLIT; ++cc)
        M = fmaxf(M, pb[cc * PART_STRIDE + 512 + g]);
    float L = 0.0f, O0 = 0.0f, O1 = 0.0f;
    #pragma unroll
    for (int cc = 0; cc < NSPLIT; ++cc) {
        float mc = pb[cc * PART_STRIDE + 512 + g];
        float sc = __expf(mc - M);                    // empty chunk -> 0
        L  += pb[cc * PART_STRIDE + 516 + g] * sc;
        O0 += pb[cc * PART_STRIDE + g * HD + d2]     * sc;
        O1 += pb[cc * PART_STRIDE + g * HD + d2 + 1] * sc;
    }
    float inv = 1.0f / L;                             // L>0: chunk 0 always non-empty
    const int h = kvh * NG + g;
    out[((size_t)b * NH + h) * HD + d2]     = O0 * inv;
    out[((size_t)b * NH + h) * HD + d2 + 1] = O1 * inv;
}

extern "C" void kernel_launch(void* const* d_in, const int* in_sizes, int n_in,
                              void* d_out, int out_size, void* d_ws, size_t ws_size,
                              hipStream_t stream)
{
    const float* q   = (const float*)d_in[0];
    const float* kc  = (const float*)d_in[1];
    const float* vc  = (const float*)d_in[2];
    const int*   kvl = (const int*)d_in[3];
    const int*   bt  = (const int*)d_in[4];
    float* part = (float*)d_ws;   // needs 16*8*16*520*4 B = 4.06 MB

    attn_partial_kernel<<<NB * NKVH * NSPLIT, 256, 0, stream>>>(q, kc, vc, kvl, bt, part);
    attn_combine_kernel<<<NB * NKVH, 256, 0, stream>>>(part, (float*)d_out);
}